// Round 6
// baseline (957.832 us; speedup 1.0000x reference)
//
#include <hip/hip_runtime.h>
#include <math.h>

#define NPTS 256
#define NSRC 1024
#define NITER 100
#define KCONV 577.0780163555854f         // log2(e)/eps
#define INV_KC 0.0017328679513998632f    // eps*ln2
#define EPS_LBC (-0.013862943611198906f) // eps*ln(1/256)
#define EPSQ 0.0025f
#define NEG_BIG (-1e30f)

#define TAGM 127u
#define WS_PART_W 32768                  // u32-word offset of per-block partial sums
#define WS_MEMSET_BYTES 131072           // 8 img * 2 par * 256 j * 8 b * 4B

#define EXP2F(x) __builtin_amdgcn_exp2f(x)
#define LOG2F(x) __builtin_amdgcn_logf(x)
#define F4E(v,e) ((e)==0?(v).x:(e)==1?(v).y:(e)==2?(v).z:(v).w)

// tagged agent-scope (IF$-coherent) partial: f32 with low 7 mantissa bits = tag
__device__ __forceinline__ void stp(unsigned int* p, float t, unsigned int tag) {
  unsigned int u = (__float_as_uint(t) & ~TAGM) | tag;
  __hip_atomic_store(p, u, __ATOMIC_RELAXED, __HIP_MEMORY_SCOPE_AGENT);
}
__device__ __forceinline__ unsigned int ldp(const unsigned int* p) {
  return __hip_atomic_load(p, __ATOMIC_RELAXED, __HIP_MEMORY_SCOPE_AGENT);
}

__global__ __launch_bounds__(1024)
void ot_sinkhorn(const float* __restrict__ dens_all,
                 const float* __restrict__ pts_all,
                 unsigned int* __restrict__ wsu)
{
  __shared__ __align__(16) float pxL[NPTS], pyL[NPTS];
  __shared__ __align__(16) float pxP[16 * 20], pyP[16 * 20];
  __shared__ __align__(16) float GcL[16 * 20];
  __shared__ __align__(16) float F_loc[128];
  __shared__ __align__(16) float aLc[128], elaLc[128];
  __shared__ __align__(16) float Fb[NPTS], Gb[NPTS];      // bb
  __shared__ __align__(16) float FaL[NSRC];               // aa
  __shared__ __align__(16) float TaL[32 * 33];
  __shared__ __align__(16) float PM[16 * 33];
  __shared__ __align__(16) float CM[32];
  __shared__ float red[16];

  const int tid = threadIdx.x;
  const int bid = blockIdx.x;
  float* partials = (float*)(wsu + WS_PART_W);

  float acc = 0.0f;

  if (bid < 64) {
    // ============ ot_ab : 8 teams x 8 blocks, ONE tagged exchange per iteration ============
    const int img = bid >> 3, sub = bid & 7;
    const float* dens = dens_all + img * NSRC;
    const float* pts = pts_all + img * (NPTS * 2);
    unsigned int* P = wsu + img * 4096;        // [par][j][b] : par*2048 + j*8 + b

    if (tid < NPTS) {
      float px = pts[2 * tid], py = pts[2 * tid + 1];
      pxL[tid] = px; pyL[tid] = py;
      pxP[(tid >> 4) * 20 + (tid & 15)] = px;
      pyP[(tid >> 4) * 20 + (tid & 15)] = py;
    }
    if (tid < 128) {
      int c = sub * 128 + tid;
      float a = dens[c];
      aLc[tid] = a;
      float ela = (a > 0.0f) ? EPSQ * __logf(a) : NEG_BIG;
      elaLc[tid] = ela;
      F_loc[tid] = ela;                         // f = 0 (t-units)
    }
    __syncthreads();

    // merge/partial geometry: 4 lanes per target, slice s4 owns grid row sub*4+s4
    const int w = tid >> 6, lane = tid & 63;
    const int jm = w * 16 + (lane >> 2), s4 = lane & 3;
    const float pxj = pxL[jm], pyj = pyL[jm];
    const float dyp = (float)((sub * 4 + s4) * 8 + 4) - pyj;
    const float dy2p = dyp * dyp;
    const float dx0p = 4.0f - pxj;
    // f-update geometry: 8 lanes per cell, 128 cells
    const int cl = tid >> 3, ch = tid & 7;
    const float cx = (float)((cl & 31) * 8 + 4);
    const float cy = (float)((sub * 4 + (cl >> 5)) * 8 + 4);
    const float a_c = aLc[cl], ela_c = elaLc[cl];

    const float4* GcL4 = (const float4*)GcL;
    const float4* pxP4 = (const float4*)pxP;
    const float4* pyP4 = (const float4*)pyP;
    const float4* Fl4  = (const float4*)F_loc;

    float tt[32];

    auto partial_store = [&](int tag) {
      float m = -INFINITY;
      #pragma unroll
      for (int q = 0; q < 8; ++q) {
        float4 Fv = Fl4[s4 * 8 + q];
        #pragma unroll
        for (int e = 0; e < 4; ++e) {
          float dx = dx0p + (float)((q * 4 + e) * 8);
          float v = fmaf(fmaf(dx, dx, dy2p), -0.5f, F4E(Fv, e));
          tt[q * 4 + e] = v; m = fmaxf(m, v);
        }
      }
      m = fmaxf(m, __shfl_xor(m, 1, 64));
      m = fmaxf(m, __shfl_xor(m, 2, 64));
      const float mk = m * KCONV;
      float s = 0.0f;
      #pragma unroll
      for (int i = 0; i < 32; ++i) s += EXP2F(fmaf(tt[i], KCONV, -mk));
      s += __shfl_xor(s, 1, 64);
      s += __shfl_xor(s, 2, 64);
      if (s4 == 0)
        stp(P + (tag & 1) * 2048 + jm * 8 + sub, m + LOG2F(s) * INV_KC, (unsigned)tag);
    };

    auto g_merge = [&](int k) -> float {
      const unsigned int* pp = P + (k & 1) * 2048 + jm * 8 + s4 * 2;
      unsigned int u0, u1;
      for (;;) {
        u0 = ldp(pp); u1 = ldp(pp + 1);
        bool ok = ((u0 & TAGM) == (unsigned)k) && ((u1 & TAGM) == (unsigned)k);
        if (__all(ok)) break;
        __builtin_amdgcn_s_sleep(1);
      }
      float t0 = __uint_as_float(u0 & ~TAGM), t1 = __uint_as_float(u1 & ~TAGM);
      float m = fmaxf(t0, t1);
      float s = EXP2F((t0 - m) * KCONV) + EXP2F((t1 - m) * KCONV);
      #pragma unroll
      for (int o = 1; o < 4; o <<= 1) {
        float mo = __shfl_xor(m, o, 64), so = __shfl_xor(s, o, 64);
        float mn = fmaxf(m, mo);
        s = s * EXP2F((m - mn) * KCONV) + so * EXP2F((mo - mn) * KCONV);
        m = mn;
      }
      return -(m + LOG2F(s) * INV_KC);
    };

    partial_store(1);
    for (int k = 1; k <= NITER; ++k) {
      float g = g_merge(k);
      if (s4 == 0) GcL[(jm >> 4) * 20 + (jm & 15)] = g + EPS_LBC;
      __syncthreads();
      // ---- f-update over all 256 targets for this block's 128 cells ----
      {
        float m = -INFINITY;
        #pragma unroll
        for (int q = 0; q < 8; ++q) {
          int gi = 2 * ch + (q >> 2);
          float4 pxv = pxP4[gi * 5 + (q & 3)];
          float4 pyv = pyP4[gi * 5 + (q & 3)];
          float4 Gv  = GcL4[gi * 5 + (q & 3)];
          #pragma unroll
          for (int e = 0; e < 4; ++e) {
            float dx = F4E(pxv, e) - cx;
            float dyq = F4E(pyv, e) - cy;
            float u = fmaf(dyq, dyq, dx * dx);
            float v = fmaf(u, -0.5f, F4E(Gv, e));
            tt[q * 4 + e] = v; m = fmaxf(m, v);
          }
        }
        m = fmaxf(m, __shfl_xor(m, 1, 64));
        m = fmaxf(m, __shfl_xor(m, 2, 64));
        m = fmaxf(m, __shfl_xor(m, 4, 64));
        const float mk = m * KCONV;
        float s = 0.0f;
        #pragma unroll
        for (int i = 0; i < 32; ++i) s += EXP2F(fmaf(tt[i], KCONV, -mk));
        s += __shfl_xor(s, 1, 64);
        s += __shfl_xor(s, 2, 64);
        s += __shfl_xor(s, 4, 64);
        if (ch == 0) {
          float f = -(m + LOG2F(s) * INV_KC);
          F_loc[cl] = f + ela_c;
          if (k == NITER) acc += a_c * f;      // f_100
        }
      }
      __syncthreads();
      partial_store(k + 1);
    }
    {
      float g = g_merge(NITER + 1);            // g_101
      if (s4 == 0 && (jm >> 5) == sub) acc += g * (1.0f / 256.0f);
    }
  } else if (bid < 72) {
    // ============ ot_bb : one block, in-LDS ============
    const int img = bid - 64;
    const float* pts = pts_all + img * (NPTS * 2);
    if (tid < NPTS) {
      pxL[tid] = pts[2 * tid];
      pyL[tid] = pts[2 * tid + 1];
      Fb[tid] = EPS_LBC;                        // f = 0
    }
    __syncthreads();

    const int cl = tid >> 4, ch = tid & 15;
    float4 px4[4], py4[4];
    #pragma unroll
    for (int k = 0; k < 4; ++k) {
      px4[k] = *(const float4*)(pxL + ch * 16 + k * 4);
      py4[k] = *(const float4*)(pyL + ch * 16 + k * 4);
    }
    const float4* Fb4 = (const float4*)Fb;
    const float4* Gb4 = (const float4*)Gb;

    float tt[16];
    for (int it = 0;; ++it) {
      float4 A4[4];
      #pragma unroll
      for (int k = 0; k < 4; ++k) A4[k] = Fb4[ch * 4 + k];
      #pragma unroll 1
      for (int p = 0; p < 4; ++p) {
        const int tj = p * 64 + cl;
        const float qx = pxL[tj], qy = pyL[tj];
        float m = -INFINITY;
        #pragma unroll
        for (int k = 0; k < 4; ++k) {
          #pragma unroll
          for (int e = 0; e < 4; ++e) {
            float dx = F4E(px4[k], e) - qx;
            float dyq = F4E(py4[k], e) - qy;
            float u = fmaf(dyq, dyq, dx * dx);
            float v = fmaf(u, -0.5f, F4E(A4[k], e));
            tt[k * 4 + e] = v; m = fmaxf(m, v);
          }
        }
        #pragma unroll
        for (int o = 1; o < 16; o <<= 1) m = fmaxf(m, __shfl_xor(m, o, 64));
        const float mk = m * KCONV;
        float s = 0.0f;
        #pragma unroll
        for (int i = 0; i < 16; ++i) s += EXP2F(fmaf(tt[i], KCONV, -mk));
        #pragma unroll
        for (int o = 1; o < 16; o <<= 1) s += __shfl_xor(s, o, 64);
        const float g = -(m + LOG2F(s) * INV_KC);
        if (it == NITER) { if (ch == 0) acc += g * (1.0f / 256.0f); }
        else if (ch == 0) Gb[tj] = g + EPS_LBC;
      }
      if (it == NITER) break;
      __syncthreads();

      float4 B4[4];
      #pragma unroll
      for (int k = 0; k < 4; ++k) B4[k] = Gb4[ch * 4 + k];
      #pragma unroll 1
      for (int p = 0; p < 4; ++p) {
        const int tj = p * 64 + cl;
        const float qx = pxL[tj], qy = pyL[tj];
        float m = -INFINITY;
        #pragma unroll
        for (int k = 0; k < 4; ++k) {
          #pragma unroll
          for (int e = 0; e < 4; ++e) {
            float dx = F4E(px4[k], e) - qx;
            float dyq = F4E(py4[k], e) - qy;
            float u = fmaf(dyq, dyq, dx * dx);
            float v = fmaf(u, -0.5f, F4E(B4[k], e));
            tt[k * 4 + e] = v; m = fmaxf(m, v);
          }
        }
        #pragma unroll
        for (int o = 1; o < 16; o <<= 1) m = fmaxf(m, __shfl_xor(m, o, 64));
        const float mk = m * KCONV;
        float s = 0.0f;
        #pragma unroll
        for (int i = 0; i < 16; ++i) s += EXP2F(fmaf(tt[i], KCONV, -mk));
        #pragma unroll
        for (int o = 1; o < 16; o <<= 1) s += __shfl_xor(s, o, 64);
        if (ch == 0) {
          const float f = -(m + LOG2F(s) * INV_KC);
          Fb[tj] = f + EPS_LBC;
          if (it == NITER - 1) acc += f * (1.0f / 256.0f);
        }
      }
      __syncthreads();
    }
  } else {
    // ============ ot_aa : one block, separable LSE + verified diagonal collapse ============
    const int img = bid - 72;
    const float* dens = dens_all + img * NSRC;
    const float d_np = dens[tid];
    const float a_np = d_np;
    const float epsla_np = (d_np > 0.0f) ? EPSQ * __logf(d_np) : NEG_BIG;
    float myF = epsla_np;
    FaL[tid] = myF;
    __syncthreads();

    const int w = tid >> 6, lane = tid & 63;
    const int q1 = tid & 31, r1 = tid >> 5;
    const int q2 = q1, r2 = r1;

    auto aa_half = [&]() -> float {
      float cp = fmaxf(myF, __shfl_xor(myF, 32, 64));
      if (lane < 32) PM[w * 33 + lane] = cp;
      __syncthreads();
      if (tid < 32) {
        float cm = -INFINITY;
        #pragma unroll
        for (int w2 = 0; w2 < 16; ++w2) cm = fmaxf(cm, PM[w2 * 33 + tid]);
        CM[tid] = cm;
      }
      __syncthreads();
      const float fmx = CM[q1];
      float Tv;
      if (__all(fmx - 32.0f <= myF - 0.25f)) {
        Tv = myF;
      } else {
        float tv[32]; float m = -INFINITY; float d = (float)(-r1);
        #pragma unroll
        for (int rr = 0; rr < 32; ++rr) {
          float v = fmaf(d * d, -32.0f, FaL[rr * 32 + q1]);
          tv[rr] = v; m = fmaxf(m, v); d += 1.0f;
        }
        const float mk = m * KCONV; float s = 0.0f;
        #pragma unroll
        for (int rr = 0; rr < 32; ++rr) s += EXP2F(fmaf(tv[rr], KCONV, -mk));
        Tv = m + LOG2F(s) * INV_KC;
      }
      TaL[q1 * 33 + r1] = Tv;
      __syncthreads();
      float tmx = Tv;
      #pragma unroll
      for (int o = 1; o < 32; o <<= 1) tmx = fmaxf(tmx, __shfl_xor(tmx, o, 64));
      float outv;
      if (__all(tmx - 32.0f <= Tv - 0.25f)) {
        outv = Tv;
      } else {
        float tv[32]; float m = -INFINITY; float d = (float)(-q2);
        #pragma unroll
        for (int qi = 0; qi < 32; ++qi) {
          float v = fmaf(d * d, -32.0f, TaL[qi * 33 + r2]);
          tv[qi] = v; m = fmaxf(m, v); d += 1.0f;
        }
        const float mk = m * KCONV; float s = 0.0f;
        #pragma unroll
        for (int qi = 0; qi < 32; ++qi) s += EXP2F(fmaf(tv[qi], KCONV, -mk));
        outv = m + LOG2F(s) * INV_KC;
      }
      return -outv;
    };

    for (int it = 0;; ++it) {
      float gpot = aa_half();
      if (it == NITER) { acc += a_np * gpot; break; }
      myF = gpot + epsla_np; FaL[tid] = myF;
      __syncthreads();
      float fpot = aa_half();
      if (it == NITER - 1) acc += a_np * fpot;
      myF = fpot + epsla_np; FaL[tid] = myF;
      __syncthreads();
    }
  }

  // ---- block reduction + per-block partial ----
  {
    #pragma unroll
    for (int o = 32; o; o >>= 1) acc += __shfl_xor(acc, o, 64);
    __syncthreads();
    if ((tid & 63) == 0) red[tid >> 6] = acc;
    __syncthreads();
    if (tid == 0) {
      float tsum = 0.0f;
      #pragma unroll
      for (int k = 0; k < 16; ++k) tsum += red[k];
      partials[bid] = tsum;
    }
  }
}

__global__ void ot_finalize(const float* __restrict__ partials, float* __restrict__ out) {
  __shared__ float red2[2];
  const int tid = threadIdx.x;
  float v = 0.0f;
  if (tid < 80) v = ((tid < 64) ? 1.0f : -0.5f) * partials[tid];
  #pragma unroll
  for (int o = 32; o; o >>= 1) v += __shfl_xor(v, o, 64);
  if ((tid & 63) == 0) red2[tid >> 6] = v;
  __syncthreads();
  if (tid == 0) out[0] = red2[0] + red2[1];
}

extern "C" void kernel_launch(void* const* d_in, const int* in_sizes, int n_in,
                              void* d_out, int out_size, void* d_ws, size_t ws_size,
                              hipStream_t stream) {
  const float* dens = (const float*)d_in[0];   // (8,1,32,32) f32
  const float* pts  = (const float*)d_in[1];   // (8,256,2)   f32
  unsigned int* wsu = (unsigned int*)d_ws;
  (void)hipMemsetAsync(d_ws, 0, WS_MEMSET_BYTES, stream);   // zero tagged-partial region
  ot_sinkhorn<<<dim3(80), dim3(1024), 0, stream>>>(dens, pts, wsu);
  ot_finalize<<<dim3(1), dim3(128), 0, stream>>>((const float*)(wsu + WS_PART_W), (float*)d_out);
}

// Round 7
// 643.003 us; speedup vs baseline: 1.4896x; 1.4896x over previous
//
#include <hip/hip_runtime.h>
#include <math.h>

#define NPTS 256
#define NSRC 1024
#define NITER 100
#define KCONV 577.0780163555854f         // log2(e)/eps
#define INV_KC 0.0017328679513998632f    // eps*ln2
#define EPS_LBC (-0.013862943611198906f) // eps*ln(1/256)
#define EPSQ 0.0025f
#define NEG_BIG (-1e30f)
#define TAGM 15u

#define EXP2F(x) __builtin_amdgcn_exp2f(x)
#define LOG2F(x) __builtin_amdgcn_logf(x)
#define F4E(v,e) ((e)==0?(v).x:(e)==1?(v).y:(e)==2?(v).z:(v).w)

// exchange layout (u32 words):
//  ab img i @ i*4096:        F[par] at +par*1024 (1024 w), G[par] at +2048+par*256
//  bb img i @ 32768+i*1024:  F[par] at +par*256,           G[par] at +512+par*256
//  partials (float) at word 40960 (136 entries)
#define AB_BASE(img) ((img) * 4096)
#define BB_BASE(img) (32768 + (img) * 1024)
#define WS_PART_W 40960

__device__ __forceinline__ void stp(unsigned int* p, float v, unsigned int tag) {
  __hip_atomic_store(p, (__float_as_uint(v) & ~TAGM) | tag,
                     __ATOMIC_RELAXED, __HIP_MEMORY_SCOPE_AGENT);
}
__device__ __forceinline__ unsigned int ldp(const unsigned int* p) {
  return __hip_atomic_load(p, __ATOMIC_RELAXED, __HIP_MEMORY_SCOPE_AGENT);
}
// poll 4 consecutive tagged words until all carry tag tg; return untagged values
__device__ __forceinline__ float4 poll4(const unsigned int* p, unsigned int tg) {
  unsigned int u0, u1, u2, u3;
  for (;;) {
    u0 = ldp(p); u1 = ldp(p + 1); u2 = ldp(p + 2); u3 = ldp(p + 3);
    if (((((u0 & TAGM) ^ tg) | ((u1 & TAGM) ^ tg)) |
         (((u2 & TAGM) ^ tg) | ((u3 & TAGM) ^ tg))) == 0u) break;
    __builtin_amdgcn_s_sleep(1);
  }
  return make_float4(__uint_as_float(u0 & ~TAGM), __uint_as_float(u1 & ~TAGM),
                     __uint_as_float(u2 & ~TAGM), __uint_as_float(u3 & ~TAGM));
}

__global__ __launch_bounds__(1024)
void ot_sinkhorn(const float* __restrict__ dens_all,
                 const float* __restrict__ pts_all,
                 unsigned int* __restrict__ wsu)
{
  // ---- ab (2 image slots) ----
  __shared__ __align__(16) float FLa[2][32 * 36];
  __shared__ __align__(16) float GLa[2][16 * 20];
  __shared__ __align__(16) float pxP[2][16 * 20], pyP[2][16 * 20];
  __shared__ __align__(16) float aLc[2][64], elaLc[2][64];
  // ---- bb (2 image slots) ----
  __shared__ __align__(16) float FbL[2][16 * 20], GbL[2][16 * 20];
  __shared__ __align__(16) float pxQ[2][16 * 20], pyQ[2][16 * 20];
  // ---- aa ----
  __shared__ __align__(16) float FaL[NSRC];
  __shared__ __align__(16) float TaL[32 * 33];
  __shared__ __align__(16) float PM[16 * 33];
  __shared__ __align__(16) float CM[32];
  __shared__ float red[16];

  const int tid = threadIdx.x;
  const int bid = blockIdx.x;
  float* partials = (float*)(wsu + WS_PART_W);
  float acc = 0.0f;

  if (bid < 64) {
    // =================== ot_ab : 4 teams x 16 blocks x 2 images ===================
    const int team = bid >> 4, sub = bid & 15;
    unsigned int* EX[2] = { wsu + AB_BASE(team * 2), wsu + AB_BASE(team * 2 + 1) };

    for (int s = 0; s < 2; ++s) {
      const int img = team * 2 + s;
      const float* dens = dens_all + img * NSRC;
      const float* pts = pts_all + img * (NPTS * 2);
      if (tid < NPTS) {
        pxP[s][(tid >> 4) * 20 + (tid & 15)] = pts[2 * tid];
        pyP[s][(tid >> 4) * 20 + (tid & 15)] = pts[2 * tid + 1];
      }
      { float a = dens[tid];
        FLa[s][(tid >> 5) * 36 + (tid & 31)] = (a > 0.0f) ? EPSQ * __logf(a) : NEG_BIG; }
      if (tid < 64) {
        float a = dens[sub * 64 + tid];
        aLc[s][tid] = a;
        elaLc[s][tid] = (a > 0.0f) ? EPSQ * __logf(a) : NEG_BIG;
      }
    }
    __syncthreads();

    const int w = tid >> 6, lane = tid & 63;
    const int r = lane & 31, h = lane >> 5;
    const int jg = sub * 16 + w;                 // g-half target (one wave per target)
    const float ry = (float)(r * 8 + 4);
    const float xb = (float)(h * 128 + 4);
    const int cl = tid >> 4, ch = tid & 15;      // f-half: 16 lanes per cell
    const int cc = sub * 64 + cl;
    const float cx = (float)((cc & 31) * 8 + 4);
    const float cy = (float)((cc >> 5) * 8 + 4);

    float tt[16];
    auto ghalf = [&](int s) -> float {
      const float4* FL4 = (const float4*)FLa[s];
      const float pxj = pxP[s][(jg >> 4) * 20 + (jg & 15)];
      const float pyj = pyP[s][(jg >> 4) * 20 + (jg & 15)];
      const float dy = ry - pyj; const float dy2 = dy * dy;
      const float px0 = xb - pxj;
      float m = -INFINITY;
      #pragma unroll
      for (int k = 0; k < 4; ++k) {
        float4 Fv = FL4[r * 9 + h * 4 + k];
        #pragma unroll
        for (int e = 0; e < 4; ++e) {
          float dx = px0 + (float)(k * 32 + e * 8);
          float v = fmaf(fmaf(dx, dx, dy2), -0.5f, F4E(Fv, e));
          tt[k * 4 + e] = v; m = fmaxf(m, v);
        }
      }
      #pragma unroll
      for (int o = 1; o < 64; o <<= 1) m = fmaxf(m, __shfl_xor(m, o, 64));
      const float mk = m * KCONV;
      float ss = 0.0f;
      #pragma unroll
      for (int i = 0; i < 16; ++i) ss += EXP2F(fmaf(tt[i], KCONV, -mk));
      #pragma unroll
      for (int o = 1; o < 64; o <<= 1) ss += __shfl_xor(ss, o, 64);
      return -(m + LOG2F(ss) * INV_KC);
    };
    auto fhalf = [&](int s) -> float {
      const float4* GL4 = (const float4*)GLa[s];
      const float4* px4 = (const float4*)pxP[s];
      const float4* py4 = (const float4*)pyP[s];
      float m = -INFINITY;
      #pragma unroll
      for (int k = 0; k < 4; ++k) {
        float4 pxv = px4[ch * 5 + k], pyv = py4[ch * 5 + k], Gv = GL4[ch * 5 + k];
        #pragma unroll
        for (int e = 0; e < 4; ++e) {
          float dx = F4E(pxv, e) - cx, dq = F4E(pyv, e) - cy;
          float v = fmaf(fmaf(dq, dq, dx * dx), -0.5f, F4E(Gv, e));
          tt[k * 4 + e] = v; m = fmaxf(m, v);
        }
      }
      #pragma unroll
      for (int o = 1; o < 16; o <<= 1) m = fmaxf(m, __shfl_xor(m, o, 64));
      const float mk = m * KCONV;
      float ss = 0.0f;
      #pragma unroll
      for (int i = 0; i < 16; ++i) ss += EXP2F(fmaf(tt[i], KCONV, -mk));
      #pragma unroll
      for (int o = 1; o < 16; o <<= 1) ss += __shfl_xor(ss, o, 64);
      return -(m + LOG2F(ss) * INV_KC);
    };

    for (int k = 1; k <= NITER; ++k) {
      const unsigned int tg = (unsigned)k & TAGM;
      float gA = ghalf(0);
      if (lane == 0) stp(EX[0] + 2048 + (k & 1) * 256 + jg, gA + EPS_LBC, tg);
      float gB = ghalf(1);
      if (lane == 0) stp(EX[1] + 2048 + (k & 1) * 256 + jg, gB + EPS_LBC, tg);

      if (tid < 64) {   // poll G_A -> stage
        float4 v = poll4(EX[0] + 2048 + (k & 1) * 256 + tid * 4, tg);
        int j = tid * 4;
        *(float4*)(GLa[0] + (j >> 4) * 20 + (j & 15)) = v;
      }
      __syncthreads();
      float fA = fhalf(0);
      if (ch == 0) {
        stp(EX[0] + (k & 1) * 1024 + cc, fA + elaLc[0][cl], tg);
        if (k == NITER) acc += aLc[0][cl] * fA;
      }
      if (tid < 64) {   // poll G_B -> stage
        float4 v = poll4(EX[1] + 2048 + (k & 1) * 256 + tid * 4, tg);
        int j = tid * 4;
        *(float4*)(GLa[1] + (j >> 4) * 20 + (j & 15)) = v;
      }
      __syncthreads();
      float fB = fhalf(1);
      if (ch == 0) {
        stp(EX[1] + (k & 1) * 1024 + cc, fB + elaLc[1][cl], tg);
        if (k == NITER) acc += aLc[1][cl] * fB;
      }
      if (tid < 256) {  // poll F_A, F_B -> stage
        float4 v = poll4(EX[0] + (k & 1) * 1024 + tid * 4, tg);
        int c = tid * 4;
        *(float4*)(FLa[0] + (c >> 5) * 36 + (c & 31)) = v;
        float4 v2 = poll4(EX[1] + (k & 1) * 1024 + tid * 4, tg);
        *(float4*)(FLa[1] + (c >> 5) * 36 + (c & 31)) = v2;
      }
      __syncthreads();
    }
    { float gA = ghalf(0); if (lane == 0) acc += gA * (1.0f / 256.0f);
      float gB = ghalf(1); if (lane == 0) acc += gB * (1.0f / 256.0f); }
  } else if (bid < 128) {
    // =================== ot_bb : 4 teams x 16 blocks x 2 images ===================
    const int team = (bid - 64) >> 4, sub = (bid - 64) & 15;
    unsigned int* EX[2] = { wsu + BB_BASE(team * 2), wsu + BB_BASE(team * 2 + 1) };

    for (int s = 0; s < 2; ++s) {
      const float* pts = pts_all + (team * 2 + s) * (NPTS * 2);
      if (tid < NPTS) {
        pxQ[s][(tid >> 4) * 20 + (tid & 15)] = pts[2 * tid];
        pyQ[s][(tid >> 4) * 20 + (tid & 15)] = pts[2 * tid + 1];
        FbL[s][(tid >> 4) * 20 + (tid & 15)] = EPS_LBC;   // f = 0
      }
    }
    __syncthreads();

    const int w = tid >> 6, lane = tid & 63;
    const int jg = sub * 16 + w;
    const int lg = lane >> 2, le = lane & 3;   // lane covers sources lane*4..+3

    float tb[4];
    auto bhalf = [&](int s, const float (*POT)[320]) -> float {
      const float4* P4 = (const float4*)POT[s];
      const float4* px4 = (const float4*)pxQ[s];
      const float4* py4 = (const float4*)pyQ[s];
      const float qx = pxQ[s][(jg >> 4) * 20 + (jg & 15)];
      const float qy = pyQ[s][(jg >> 4) * 20 + (jg & 15)];
      float4 pxv = px4[lg * 5 + le], pyv = py4[lg * 5 + le], Pv = P4[lg * 5 + le];
      float m = -INFINITY;
      #pragma unroll
      for (int e = 0; e < 4; ++e) {
        float dx = F4E(pxv, e) - qx, dq = F4E(pyv, e) - qy;
        float v = fmaf(fmaf(dq, dq, dx * dx), -0.5f, F4E(Pv, e));
        tb[e] = v; m = fmaxf(m, v);
      }
      #pragma unroll
      for (int o = 1; o < 64; o <<= 1) m = fmaxf(m, __shfl_xor(m, o, 64));
      const float mk = m * KCONV;
      float ss = 0.0f;
      #pragma unroll
      for (int e = 0; e < 4; ++e) ss += EXP2F(fmaf(tb[e], KCONV, -mk));
      #pragma unroll
      for (int o = 1; o < 64; o <<= 1) ss += __shfl_xor(ss, o, 64);
      return -(m + LOG2F(ss) * INV_KC);
    };

    for (int k = 1; k <= NITER; ++k) {
      const unsigned int tg = (unsigned)k & TAGM;
      float gA = bhalf(0, FbL);
      if (lane == 0) stp(EX[0] + 512 + (k & 1) * 256 + jg, gA + EPS_LBC, tg);
      float gB = bhalf(1, FbL);
      if (lane == 0) stp(EX[1] + 512 + (k & 1) * 256 + jg, gB + EPS_LBC, tg);

      if (tid < 64) {
        float4 v = poll4(EX[0] + 512 + (k & 1) * 256 + tid * 4, tg);
        int j = tid * 4;
        *(float4*)(GbL[0] + (j >> 4) * 20 + (j & 15)) = v;
      }
      __syncthreads();
      float fA = bhalf(0, GbL);
      if (lane == 0) {
        stp(EX[0] + (k & 1) * 256 + jg, fA + EPS_LBC, tg);
        if (k == NITER) acc += fA * (1.0f / 256.0f);
      }
      if (tid < 64) {
        float4 v = poll4(EX[1] + 512 + (k & 1) * 256 + tid * 4, tg);
        int j = tid * 4;
        *(float4*)(GbL[1] + (j >> 4) * 20 + (j & 15)) = v;
      }
      __syncthreads();
      float fB = bhalf(1, GbL);
      if (lane == 0) {
        stp(EX[1] + (k & 1) * 256 + jg, fB + EPS_LBC, tg);
        if (k == NITER) acc += fB * (1.0f / 256.0f);
      }
      if (tid < 64) {
        float4 v = poll4(EX[0] + (k & 1) * 256 + tid * 4, tg);
        int j = tid * 4;
        *(float4*)(FbL[0] + (j >> 4) * 20 + (j & 15)) = v;
        float4 v2 = poll4(EX[1] + (k & 1) * 256 + tid * 4, tg);
        *(float4*)(FbL[1] + (j >> 4) * 20 + (j & 15)) = v2;
      }
      __syncthreads();
    }
    { float gA = bhalf(0, FbL); if (lane == 0) acc += gA * (1.0f / 256.0f);
      float gB = bhalf(1, FbL); if (lane == 0) acc += gB * (1.0f / 256.0f); }
  } else {
    // =================== ot_aa : one block, separable LSE + diagonal collapse ===================
    const int img = bid - 128;
    const float* dens = dens_all + img * NSRC;
    const float d_np = dens[tid];
    const float a_np = d_np;
    const float epsla_np = (d_np > 0.0f) ? EPSQ * __logf(d_np) : NEG_BIG;
    float myF = epsla_np;
    FaL[tid] = myF;
    __syncthreads();

    const int w = tid >> 6, lane = tid & 63;
    const int q1 = tid & 31, r1 = tid >> 5;
    const int q2 = q1, r2 = r1;

    auto aa_half = [&]() -> float {
      float cp = fmaxf(myF, __shfl_xor(myF, 32, 64));
      if (lane < 32) PM[w * 33 + lane] = cp;
      __syncthreads();
      if (tid < 32) {
        float cm = -INFINITY;
        #pragma unroll
        for (int w2 = 0; w2 < 16; ++w2) cm = fmaxf(cm, PM[w2 * 33 + tid]);
        CM[tid] = cm;
      }
      __syncthreads();
      const float fmx = CM[q1];
      float Tv;
      if (__all(fmx - 32.0f <= myF - 0.25f)) {
        Tv = myF;
      } else {
        float tv[32]; float m = -INFINITY; float d = (float)(-r1);
        #pragma unroll
        for (int rr = 0; rr < 32; ++rr) {
          float v = fmaf(d * d, -32.0f, FaL[rr * 32 + q1]);
          tv[rr] = v; m = fmaxf(m, v); d += 1.0f;
        }
        const float mk = m * KCONV; float s = 0.0f;
        #pragma unroll
        for (int rr = 0; rr < 32; ++rr) s += EXP2F(fmaf(tv[rr], KCONV, -mk));
        Tv = m + LOG2F(s) * INV_KC;
      }
      TaL[q1 * 33 + r1] = Tv;
      __syncthreads();
      float tmx = Tv;
      #pragma unroll
      for (int o = 1; o < 32; o <<= 1) tmx = fmaxf(tmx, __shfl_xor(tmx, o, 64));
      float outv;
      if (__all(tmx - 32.0f <= Tv - 0.25f)) {
        outv = Tv;
      } else {
        float tv[32]; float m = -INFINITY; float d = (float)(-q2);
        #pragma unroll
        for (int qi = 0; qi < 32; ++qi) {
          float v = fmaf(d * d, -32.0f, TaL[qi * 33 + r2]);
          tv[qi] = v; m = fmaxf(m, v); d += 1.0f;
        }
        const float mk = m * KCONV; float s = 0.0f;
        #pragma unroll
        for (int qi = 0; qi < 32; ++qi) s += EXP2F(fmaf(tv[qi], KCONV, -mk));
        outv = m + LOG2F(s) * INV_KC;
      }
      __syncthreads();
      return -outv;
    };

    for (int it = 0;; ++it) {
      float gpot = aa_half();
      if (it == NITER) { acc += a_np * gpot; break; }
      myF = gpot + epsla_np; FaL[tid] = myF;
      __syncthreads();
      float fpot = aa_half();
      if (it == NITER - 1) acc += a_np * fpot;
      myF = fpot + epsla_np; FaL[tid] = myF;
      __syncthreads();
    }
  }

  // ---- block reduction + per-block partial ----
  {
    #pragma unroll
    for (int o = 32; o; o >>= 1) acc += __shfl_xor(acc, o, 64);
    __syncthreads();
    if ((tid & 63) == 0) red[tid >> 6] = acc;
    __syncthreads();
    if (tid == 0) {
      float tsum = 0.0f;
      #pragma unroll
      for (int k = 0; k < 16; ++k) tsum += red[k];
      partials[bid] = tsum;
    }
  }
}

__global__ void ot_finalize(const float* __restrict__ partials, float* __restrict__ out) {
  __shared__ float red2[3];
  const int tid = threadIdx.x;
  float v = 0.0f;
  if (tid < 136) v = ((tid < 64) ? 1.0f : -0.5f) * partials[tid];
  #pragma unroll
  for (int o = 32; o; o >>= 1) v += __shfl_xor(v, o, 64);
  if ((tid & 63) == 0) red2[tid >> 6] = v;
  __syncthreads();
  if (tid == 0) out[0] = red2[0] + red2[1] + red2[2];
}

extern "C" void kernel_launch(void* const* d_in, const int* in_sizes, int n_in,
                              void* d_out, int out_size, void* d_ws, size_t ws_size,
                              hipStream_t stream) {
  const float* dens = (const float*)d_in[0];   // (8,1,32,32) f32
  const float* pts  = (const float*)d_in[1];   // (8,256,2)   f32
  unsigned int* wsu = (unsigned int*)d_ws;
  ot_sinkhorn<<<dim3(136), dim3(1024), 0, stream>>>(dens, pts, wsu);
  ot_finalize<<<dim3(1), dim3(192), 0, stream>>>((const float*)(wsu + WS_PART_W), (float*)d_out);
}